// Round 10
// baseline (292.911 us; speedup 1.0000x reference)
//
#include <hip/hip_runtime.h>

// Problem constants
#define B_ 2048
#define S_ 512
#define I_ 256
#define F_ 256
#define NG 8   // partial-groups for the W2 fold

// ---------------- workspace layout (floats) ----------------
#define OFF_W    0                        // w[B,F]
#define OFF_SW   (OFF_W + B_*F_)          // Sw[B]
#define OFF_RP   (OFF_SW + B_)            // rp[NG][512]
#define OFF_RH   (OFF_RP + NG*512)        // rh[256]   (folded r_h)
#define OFF_RV   (OFF_RH + 256)           // rv[256]   (folded r_v)
#define OFF_SC   (OFF_RV + 256)           // sc[2]: R, c0
#define OFF_U    531456                   // u[B,S]  (16B aligned)
#define OFF_P    (OFF_U + B_*S_)          // p[B,S]
// end = 2,628,608 floats = 10.51 MB (proven budget)

// ---------------------------------------------------------------------------
// k_pre: blocks [0,512)  : w[b,f] = hidden[b,:].W1[f,:], Sw[b] (4 batches/blk)
//        blocks [512,520): rp partial fold of r = Wfc@W2
// (byte-identical to R5)
__global__ __launch_bounds__(256) void k_pre(
    const float* __restrict__ hidden, const float* __restrict__ W1,
    const float* __restrict__ W2, const float* __restrict__ Wfc,
    float* __restrict__ ws) {
  const int tid = threadIdx.x;

  if (blockIdx.x >= B_ / 4) {
    const int g = blockIdx.x - B_ / 4;
    float acc0 = 0.f, acc1 = 0.f;
#pragma unroll 8
    for (int ii = 0; ii < 32; ++ii) {
      const int i = g * 32 + ii;
      const float f = Wfc[i];
      acc0 += f * W2[(size_t)i * (I_ + F_) + tid];
      acc1 += f * W2[(size_t)i * (I_ + F_) + tid + 256];
    }
    ws[OFF_RP + g * 512 + tid] = acc0;        // r_h partial
    ws[OFF_RP + g * 512 + 256 + tid] = acc1;  // r_v partial
    return;
  }

  __shared__ float h[4][I_];
  __shared__ float red[256];
  const int b0 = blockIdx.x * 4;
#pragma unroll
  for (int k = 0; k < 4; ++k) h[k][tid] = hidden[(size_t)(b0 + k) * I_ + tid];
  __syncthreads();

  const int f = tid;
  const float4* wrow = (const float4*)(W1 + (size_t)f * I_);
  float acc[4] = {0.f, 0.f, 0.f, 0.f};
#pragma unroll 4
  for (int iq = 0; iq < I_ / 4; ++iq) {
    const float4 v = wrow[iq];
    const int i = 4 * iq;
#pragma unroll
    for (int k = 0; k < 4; ++k)
      acc[k] += v.x * h[k][i] + v.y * h[k][i + 1] + v.z * h[k][i + 2] + v.w * h[k][i + 3];
  }
#pragma unroll
  for (int k = 0; k < 4; ++k) ws[OFF_W + (size_t)(b0 + k) * F_ + f] = acc[k];

#pragma unroll
  for (int k = 0; k < 4; ++k) {
    red[tid] = acc[k];
    __syncthreads();
    for (int s = 128; s > 0; s >>= 1) { if (tid < s) red[tid] += red[tid + s]; __syncthreads(); }
    if (tid == 0) ws[OFF_SW + b0 + k] = red[0];
    __syncthreads();
  }
}

// ---------------------------------------------------------------------------
// k_mid: one block. Fold rh[x], rv[x] from partials; R = sum(rv);
// c0 = Wfc.b2 + bfc. (Same reduce order as R5's per-block fold.)
__global__ __launch_bounds__(256) void k_mid(
    const float* __restrict__ Wfc, const float* __restrict__ b2,
    const float* __restrict__ bfc, float* __restrict__ ws) {
  const int tid = threadIdx.x;
  const int lane = tid & 63;
  const int wid = tid >> 6;
  __shared__ float redA[4], redB[4];

  float rh = 0.f, rv = 0.f;
#pragma unroll
  for (int g = 0; g < NG; ++g) {
    rh += ws[OFF_RP + g * 512 + tid];
    rv += ws[OFF_RP + g * 512 + 256 + tid];
  }
  ws[OFF_RH + tid] = rh;
  ws[OFF_RV + tid] = rv;

  float t0 = rv, t1 = Wfc[tid] * b2[tid];
#pragma unroll
  for (int m = 32; m >= 1; m >>= 1) {
    t0 += __shfl_xor(t0, m, 64);
    t1 += __shfl_xor(t1, m, 64);
  }
  if (lane == 0) { redA[wid] = t0; redB[wid] = t1; }
  __syncthreads();
  if (tid == 0) {
    ws[OFF_SC + 0] = redA[0] + redA[1] + redA[2] + redA[3];           // R
    ws[OFF_SC + 1] = redB[0] + redB[1] + redB[2] + redB[3] + bfc[0];  // c0
  }
}

// ---------------------------------------------------------------------------
// K1: single pass over inp (1 GB). R5 streaming body, but rv precomputed:
// no fold, no LDS, no barrier — blocks start streaming immediately.
//   u[b,t] = inp[b,t,:].w[b,:]   p[b,t] = inp[b,t,:].rv[:]
__global__ __launch_bounds__(256) void k1_scan(
    const float* __restrict__ inp, const float* __restrict__ wsw,
    const float* __restrict__ wsrv,
    float* __restrict__ wsu, float* __restrict__ wsp) {
  const int ROWS = 32;
  const int b = blockIdx.y;
  const int t0 = blockIdx.x * ROWS;
  const int tid = threadIdx.x;
  const int lane = tid & 63;
  const int wid = tid >> 6;

  const float4 w4  = ((const float4*)(wsw + (size_t)b * F_))[lane];  // L1/L2 hit
  const float4 rv4 = ((const float4*)wsrv)[lane];                    // L2 hit
  const float* base = inp + ((size_t)b * S_ + t0) * I_;
  float* uo = wsu + (size_t)b * S_ + t0;
  float* po = wsp + (size_t)b * S_ + t0;

#pragma unroll
  for (int rr = 0; rr < ROWS / 4; ++rr) {
    const int row = wid + 4 * rr;
    const float4 in4 = ((const float4*)(base + (size_t)row * I_))[lane];
    float du = in4.x * w4.x + in4.y * w4.y + in4.z * w4.z + in4.w * w4.w;
    float dp = in4.x * rv4.x + in4.y * rv4.y + in4.z * rv4.z + in4.w * rv4.w;
#pragma unroll
    for (int m = 32; m >= 1; m >>= 1) {
      du += __shfl_xor(du, m, 64);
      dp += __shfl_xor(dp, m, 64);
    }
    if (lane == 0) { uo[row] = du; po[row] = dp; }
  }
}

// ---------------------------------------------------------------------------
// K2 v3: NO LDS staging. u,p read via wave-uniform addresses (scalar/L1
// broadcast path — off the LDS pipe). Wc keeps R5's proven per-thread-row
// pattern. rh/R/c0 precomputed by k_mid.
__global__ __launch_bounds__(256) void k2_epilogue(
    const float* __restrict__ Wc, const float* __restrict__ bc,
    const float* __restrict__ hidden,
    const float* __restrict__ wsu, const float* __restrict__ wsp,
    const float* __restrict__ wsSw, const float* __restrict__ wsrh,
    const float* __restrict__ wssc, float* __restrict__ out) {
  const int b0 = blockIdx.x * 4;
  const int x = threadIdx.x;
  const int lane = x & 63;
  const int wid = x >> 6;
  __shared__ float wred[4][4];

  const float R  = wssc[0];
  const float c0 = wssc[1];
  const float rh = wsrh[x];

  const float4* wrow = (const float4*)(Wc + (size_t)x * S_);
  const float* ub = wsu + (size_t)b0 * S_;
  const float* pb = wsp + (size_t)b0 * S_;
  float ss[4] = {0.f, 0.f, 0.f, 0.f};
  float qs[4] = {0.f, 0.f, 0.f, 0.f};
#pragma unroll 4
  for (int tq = 0; tq < S_ / 4; ++tq) {
    const float4 v = wrow[tq];
    const int t = 4 * tq;
#pragma unroll
    for (int k = 0; k < 4; ++k) {
      const float4 u4 = *(const float4*)(ub + (size_t)k * S_ + t);  // uniform
      const float4 p4 = *(const float4*)(pb + (size_t)k * S_ + t);  // uniform
      ss[k] += v.x * u4.x + v.y * u4.y + v.z * u4.z + v.w * u4.w;
      qs[k] += v.x * p4.x + v.y * p4.y + v.z * p4.z + v.w * p4.w;
    }
  }

  const float bcx = bc[x];
#pragma unroll
  for (int k = 0; k < 4; ++k) {
    const float Sw = wsSw[b0 + k];
    const float s = ss[k] + bcx * Sw;
    const float a = 1.f / (1.f + expf(-s));
    float partial = a * (qs[k] + bcx * R) + rh * hidden[(size_t)(b0 + k) * I_ + x];
#pragma unroll
    for (int m = 32; m >= 1; m >>= 1) partial += __shfl_xor(partial, m, 64);
    if (lane == 0) wred[k][wid] = partial;
  }
  __syncthreads();
  if (x < 4)
    out[b0 + x] = wred[x][0] + wred[x][1] + wred[x][2] + wred[x][3] + c0;
}

// ---------------------------------------------------------------------------
extern "C" void kernel_launch(void* const* d_in, const int* in_sizes, int n_in,
                              void* d_out, int out_size, void* d_ws, size_t ws_size,
                              hipStream_t stream) {
  (void)in_sizes; (void)n_in; (void)out_size; (void)ws_size;
  const float* hidden = (const float*)d_in[0];
  const float* inp    = (const float*)d_in[1];
  const float* W1     = (const float*)d_in[2];
  const float* Wc     = (const float*)d_in[3];
  const float* bc     = (const float*)d_in[4];
  const float* W2     = (const float*)d_in[5];
  const float* b2     = (const float*)d_in[6];
  const float* Wfc    = (const float*)d_in[7];
  const float* bfc    = (const float*)d_in[8];
  float* out = (float*)d_out;
  float* ws  = (float*)d_ws;

  hipLaunchKernelGGL(k_pre, dim3(B_ / 4 + NG), dim3(256), 0, stream,
                     hidden, W1, W2, Wfc, ws);
  hipLaunchKernelGGL(k_mid, dim3(1), dim3(256), 0, stream, Wfc, b2, bfc, ws);
  hipLaunchKernelGGL(k1_scan, dim3(S_ / 32, B_), dim3(256), 0, stream,
                     inp, ws + OFF_W, ws + OFF_RV, ws + OFF_U, ws + OFF_P);
  hipLaunchKernelGGL(k2_epilogue, dim3(B_ / 4), dim3(256), 0, stream,
                     Wc, bc, hidden, ws + OFF_U, ws + OFF_P,
                     ws + OFF_SW, ws + OFF_RH, ws + OFF_SC, out);
}

// Round 11
// 264.841 us; speedup vs baseline: 1.1060x; 1.1060x over previous
//
#include <hip/hip_runtime.h>

// Problem constants
#define B_ 2048
#define S_ 512
#define I_ 256
#define F_ 256
#define NG 8   // partial-groups for the W2 fold

// ---------------- workspace layout (floats) ----------------
#define OFF_W    0                        // w[B,F]
#define OFF_SW   (OFF_W + B_*F_)          // Sw[B]
#define OFF_RP   (OFF_SW + B_)            // rp[NG][512]
#define OFF_RH   (OFF_RP + NG*512)        // rh[256]
#define OFF_RV   (OFF_RH + 256)           // rv[256]
#define OFF_SC   (OFF_RV + 256)           // sc[2]: R, c0
#define OFF_WCT  531456                   // WcT[512][256]
#define OFF_SA   (OFF_WCT + S_*F_)        // sacc[B][256]
#define OFF_QA   (OFF_SA + B_*F_)         // qacc[B][256]
// end = 1,711,104 floats = 6.85 MB (< proven 10.5 MB budget)

// ---------------------------------------------------------------------------
// k_pre: blocks [0,512)      : w[b,f] = hidden[b,:].W1[f,:], Sw[b]
//        blocks [512,520)    : rp partial fold of r = Wfc@W2
//        blocks [520,552)    : WcT[t][x] = Wc[x][t] (64x64 LDS tiles)
__global__ __launch_bounds__(256) void k_pre(
    const float* __restrict__ hidden, const float* __restrict__ W1,
    const float* __restrict__ W2, const float* __restrict__ Wfc,
    const float* __restrict__ Wc, float* __restrict__ ws) {
  const int tid = threadIdx.x;

  if (blockIdx.x >= B_ / 4 + NG) {
    __shared__ float tile[64][65];
    const int tt = blockIdx.x - (B_ / 4 + NG);
    const int x0 = (tt & 3) * 64;
    const int t0 = (tt >> 2) * 64;
    const int col = tid & 63;
    const int wid = tid >> 6;
#pragma unroll
    for (int r = 0; r < 16; ++r) {
      const int row = r * 4 + wid;
      tile[row][col] = Wc[(size_t)(x0 + row) * S_ + t0 + col];
    }
    __syncthreads();
#pragma unroll
    for (int r = 0; r < 16; ++r) {
      const int trow = r * 4 + wid;
      ws[OFF_WCT + (size_t)(t0 + trow) * F_ + x0 + col] = tile[col][trow];
    }
    return;
  }

  if (blockIdx.x >= B_ / 4) {
    const int g = blockIdx.x - B_ / 4;
    float acc0 = 0.f, acc1 = 0.f;
#pragma unroll 8
    for (int ii = 0; ii < 32; ++ii) {
      const int i = g * 32 + ii;
      const float f = Wfc[i];
      acc0 += f * W2[(size_t)i * (I_ + F_) + tid];
      acc1 += f * W2[(size_t)i * (I_ + F_) + tid + 256];
    }
    ws[OFF_RP + g * 512 + tid] = acc0;        // r_h partial
    ws[OFF_RP + g * 512 + 256 + tid] = acc1;  // r_v partial
    return;
  }

  __shared__ float h[4][I_];
  __shared__ float red[256];
  const int b0 = blockIdx.x * 4;
#pragma unroll
  for (int k = 0; k < 4; ++k) h[k][tid] = hidden[(size_t)(b0 + k) * I_ + tid];
  __syncthreads();

  const int f = tid;
  const float4* wrow = (const float4*)(W1 + (size_t)f * I_);
  float acc[4] = {0.f, 0.f, 0.f, 0.f};
#pragma unroll 4
  for (int iq = 0; iq < I_ / 4; ++iq) {
    const float4 v = wrow[iq];
    const int i = 4 * iq;
#pragma unroll
    for (int k = 0; k < 4; ++k)
      acc[k] += v.x * h[k][i] + v.y * h[k][i + 1] + v.z * h[k][i + 2] + v.w * h[k][i + 3];
  }
#pragma unroll
  for (int k = 0; k < 4; ++k) ws[OFF_W + (size_t)(b0 + k) * F_ + f] = acc[k];

#pragma unroll
  for (int k = 0; k < 4; ++k) {
    red[tid] = acc[k];
    __syncthreads();
    for (int s = 128; s > 0; s >>= 1) { if (tid < s) red[tid] += red[tid + s]; __syncthreads(); }
    if (tid == 0) ws[OFF_SW + b0 + k] = red[0];
    __syncthreads();
  }
}

// ---------------------------------------------------------------------------
// k_mid: one block. Fold rh[x], rv[x]; R = sum(rv); c0 = Wfc.b2 + bfc.
__global__ __launch_bounds__(256) void k_mid(
    const float* __restrict__ Wfc, const float* __restrict__ b2,
    const float* __restrict__ bfc, float* __restrict__ ws) {
  const int tid = threadIdx.x;
  const int lane = tid & 63;
  const int wid = tid >> 6;
  __shared__ float redA[4], redB[4];

  float rh = 0.f, rv = 0.f;
#pragma unroll
  for (int g = 0; g < NG; ++g) {
    rh += ws[OFF_RP + g * 512 + tid];
    rv += ws[OFF_RP + g * 512 + 256 + tid];
  }
  ws[OFF_RH + tid] = rh;
  ws[OFF_RV + tid] = rv;

  float t0 = rv, t1 = Wfc[tid] * b2[tid];
#pragma unroll
  for (int m = 32; m >= 1; m >>= 1) {
    t0 += __shfl_xor(t0, m, 64);
    t1 += __shfl_xor(t1, m, 64);
  }
  if (lane == 0) { redA[wid] = t0; redB[wid] = t1; }
  __syncthreads();
  if (tid == 0) {
    ws[OFF_SC + 0] = redA[0] + redA[1] + redA[2] + redA[3];           // R
    ws[OFF_SC + 1] = redB[0] + redB[1] + redB[2] + redB[3] + bfc[0];  // c0
  }
}

// ---------------------------------------------------------------------------
// k1_fused: grid (16, B). Phase A = R5 streaming body (u,p -> LDS only).
// Phase B = contract chunk against WcT (L2-resident, coalesced), atomicAdd
// partials into sacc/qacc[b][x]. No u/p HBM round trip, no serial Wc GEMM.
__global__ __launch_bounds__(256) void k1_fused(
    const float* __restrict__ inp, const float* __restrict__ wsw,
    const float* __restrict__ wsrv, const float* __restrict__ wct,
    float* __restrict__ sacc, float* __restrict__ qacc) {
  const int ROWS = 32;
  const int b = blockIdx.y;
  const int t0 = blockIdx.x * ROWS;
  const int tid = threadIdx.x;
  const int lane = tid & 63;
  const int wid = tid >> 6;

  __shared__ float u_l[ROWS];
  __shared__ float p_l[ROWS];

  const float4 w4  = ((const float4*)(wsw + (size_t)b * F_))[lane];
  const float4 rv4 = ((const float4*)wsrv)[lane];
  const float* base = inp + ((size_t)b * S_ + t0) * I_;

#pragma unroll
  for (int rr = 0; rr < ROWS / 4; ++rr) {
    const int row = wid + 4 * rr;
    const float4 in4 = ((const float4*)(base + (size_t)row * I_))[lane];
    float du = in4.x * w4.x + in4.y * w4.y + in4.z * w4.z + in4.w * w4.w;
    float dp = in4.x * rv4.x + in4.y * rv4.y + in4.z * rv4.z + in4.w * rv4.w;
#pragma unroll
    for (int m = 32; m >= 1; m >>= 1) {
      du += __shfl_xor(du, m, 64);
      dp += __shfl_xor(dp, m, 64);
    }
    if (lane == 0) { u_l[row] = du; p_l[row] = dp; }
  }
  __syncthreads();

  // Phase B: thread x = tid; WcT rows t0..t0+31, coalesced across lanes.
  const float* wcol = wct + (size_t)t0 * F_ + tid;
  float ss = 0.f, qq = 0.f;
#pragma unroll 8
  for (int j = 0; j < ROWS; ++j) {
    const float w = wcol[(size_t)j * F_];
    ss += w * u_l[j];   // LDS broadcast
    qq += w * p_l[j];
  }
  atomicAdd(&sacc[(size_t)b * F_ + tid], ss);
  atomicAdd(&qacc[(size_t)b * F_ + tid], qq);
}

// ---------------------------------------------------------------------------
// k2_small: grid B/4. Tiny epilogue: sigmoid + weighted sums + reduce.
__global__ __launch_bounds__(256) void k2_small(
    const float* __restrict__ bc, const float* __restrict__ hidden,
    const float* __restrict__ wsSw, const float* __restrict__ wsrh,
    const float* __restrict__ wssc,
    const float* __restrict__ sacc, const float* __restrict__ qacc,
    float* __restrict__ out) {
  const int b0 = blockIdx.x * 4;
  const int x = threadIdx.x;
  const int lane = x & 63;
  const int wid = x >> 6;
  __shared__ float wred[4][4];

  const float R  = wssc[0];
  const float c0 = wssc[1];
  const float rh = wsrh[x];
  const float bcx = bc[x];

#pragma unroll
  for (int k = 0; k < 4; ++k) {
    const float s = sacc[(size_t)(b0 + k) * F_ + x] + bcx * wsSw[b0 + k];
    const float a = 1.f / (1.f + expf(-s));
    float partial = a * (qacc[(size_t)(b0 + k) * F_ + x] + bcx * R)
                  + rh * hidden[(size_t)(b0 + k) * I_ + x];
#pragma unroll
    for (int m = 32; m >= 1; m >>= 1) partial += __shfl_xor(partial, m, 64);
    if (lane == 0) wred[k][wid] = partial;
  }
  __syncthreads();
  if (x < 4)
    out[b0 + x] = wred[x][0] + wred[x][1] + wred[x][2] + wred[x][3] + c0;
}

// ---------------------------------------------------------------------------
extern "C" void kernel_launch(void* const* d_in, const int* in_sizes, int n_in,
                              void* d_out, int out_size, void* d_ws, size_t ws_size,
                              hipStream_t stream) {
  (void)in_sizes; (void)n_in; (void)out_size; (void)ws_size;
  const float* hidden = (const float*)d_in[0];
  const float* inp    = (const float*)d_in[1];
  const float* W1     = (const float*)d_in[2];
  const float* Wc     = (const float*)d_in[3];
  const float* bc     = (const float*)d_in[4];
  const float* W2     = (const float*)d_in[5];
  const float* b2     = (const float*)d_in[6];
  const float* Wfc    = (const float*)d_in[7];
  const float* bfc    = (const float*)d_in[8];
  float* out = (float*)d_out;
  float* ws  = (float*)d_ws;

  // zero the atomic accumulators (graph-safe async memset)
  hipMemsetAsync(ws + OFF_SA, 0, 2ull * B_ * F_ * sizeof(float), stream);

  hipLaunchKernelGGL(k_pre, dim3(B_ / 4 + NG + 32), dim3(256), 0, stream,
                     hidden, W1, W2, Wfc, Wc, ws);
  hipLaunchKernelGGL(k_mid, dim3(1), dim3(256), 0, stream, Wfc, b2, bfc, ws);
  hipLaunchKernelGGL(k1_fused, dim3(S_ / 32, B_), dim3(256), 0, stream,
                     inp, ws + OFF_W, ws + OFF_RV, ws + OFF_WCT,
                     ws + OFF_SA, ws + OFF_QA);
  hipLaunchKernelGGL(k2_small, dim3(B_ / 4), dim3(256), 0, stream,
                     bc, hidden, ws + OFF_SW, ws + OFF_RH, ws + OFF_SC,
                     ws + OFF_SA, ws + OFF_QA, out);
}